// Round 1
// baseline (290.190 us; speedup 1.0000x reference)
//
#include <hip/hip_runtime.h>
#include <math.h>

#define BB 2
#define CC 64
#define NPTS 16384
#define KK 16
#define RR 16
#define R3 4096

// ---------------- K1: per-(b,axis) mean of xyz ----------------
__global__ void k_mean(const float* __restrict__ xyz, float* __restrict__ meanv) {
  int row = blockIdx.x;  // b*3+o, 6 rows
  const float* src = xyz + (size_t)row * NPTS;
  float s = 0.f;
  for (int i = threadIdx.x; i < NPTS; i += 256) s += src[i];
  for (int off = 32; off; off >>= 1) s += __shfl_down(s, off, 64);
  __shared__ float ls[4];
  int lane = threadIdx.x & 63, wv = threadIdx.x >> 6;
  if (lane == 0) ls[wv] = s;
  __syncthreads();
  if (threadIdx.x == 0) meanv[row] = (ls[0] + ls[1] + ls[2] + ls[3]) / (float)NPTS;
}

// ---------------- K2: voxel coords, flat index, counts, point records -------
__global__ void k_voxel(const float* __restrict__ xyz, const float* __restrict__ meanv,
                        float* __restrict__ cnts, int* __restrict__ flat,
                        float* __restrict__ ncT, float* __restrict__ rec) {
  int p = blockIdx.x * 256 + threadIdx.x;  // 0..B*N
  int b = p / NPTS, n = p % NPTS;
  float nc[3]; int vi[3];
#pragma unroll
  for (int o = 0; o < 3; ++o) {
    float v = xyz[((size_t)b * 3 + o) * NPTS + n];
    float t = (v - meanv[b * 3 + o] + 1.0f) * 0.5f * (float)RR;
    t = fminf(fmaxf(t, 0.f), (float)(RR - 1));
    nc[o] = t;
    vi[o] = (int)rintf(t);             // jnp.round = round-half-even = rintf
    rec[(size_t)p * 8 + o] = v;
    ncT[(size_t)p * 4 + o] = t;
  }
  ncT[(size_t)p * 4 + 3] = 0.f;
  int f = (vi[0] * RR + vi[1]) * RR + vi[2];
  flat[p] = f;
  atomicAdd(&cnts[b * R3 + f], 1.0f);
}

// ---------------- K3: transpose x -> xT(B,N,C), scatter sums, y1 = wp1*x ----
__global__ __launch_bounds__(256) void k_transpose(
    const float* __restrict__ x, const int* __restrict__ flat,
    const float* __restrict__ wp1, float* __restrict__ sums,
    float* __restrict__ xT, float* __restrict__ rec) {
  __shared__ float tile[64][65];
  int bi = blockIdx.x;  // 0..B*256
  int b = bi >> 8, n0 = (bi & 255) * 64;
  int t = threadIdx.x;
  int nl = t & 63, cq = t >> 6;  // cq 0..3
  int fl = flat[b * NPTS + n0 + nl];
#pragma unroll 4
  for (int it = 0; it < 16; ++it) {
    int c = it * 4 + cq;
    float v = x[((size_t)b * CC + c) * NPTS + n0 + nl];
    tile[c][nl] = v;
    atomicAdd(&sums[((size_t)b * CC + c) * R3 + fl], v);
  }
  __syncthreads();
  int cw = t & 63, nq = t >> 6;
#pragma unroll 4
  for (int it = 0; it < 16; ++it) {
    int nl2 = it * 4 + nq;
    xT[((size_t)(b * NPTS + n0 + nl2)) * 64 + cw] = tile[cw][nl2];
  }
  if (t < 64) {
    float s0 = 0.f, s1 = 0.f, s2 = 0.f;
    for (int c = 0; c < 64; ++c) {
      float v = tile[c][t];
      s0 += wp1[c] * v; s1 += wp1[64 + c] * v; s2 += wp1[128 + c] * v;
    }
    size_t pb = (size_t)(b * NPTS + n0 + t) * 8;
    rec[pb + 3] = s0; rec[pb + 4] = s1; rec[pb + 5] = s2;
    rec[pb + 6] = 0.f; rec[pb + 7] = 0.f;
  }
}

// ---------------- K4: fused depthwise conv x2 + BN + lReLU ------------------
__global__ __launch_bounds__(256) void k_conv(
    const float* __restrict__ sums, const float* __restrict__ cnts,
    const float* __restrict__ w3a, const float* __restrict__ b3a,
    const float* __restrict__ g3a, const float* __restrict__ be3a,
    const float* __restrict__ m3a, const float* __restrict__ v3a,
    const float* __restrict__ w3b, const float* __restrict__ b3b,
    const float* __restrict__ g3b, const float* __restrict__ be3b,
    const float* __restrict__ m3b, const float* __restrict__ v3b,
    float* __restrict__ gridfT) {
  __shared__ float A[5832];   // 18^3 zero-padded
  __shared__ float Bf[5832];
  int bi = blockIdx.x, b = bi >> 6, c = bi & 63;
  int t = threadIdx.x;
  for (int i = t; i < 5832; i += 256) { A[i] = 0.f; Bf[i] = 0.f; }
  __syncthreads();
  const float* sp = sums + ((size_t)b * CC + c) * R3;
  const float* cp = cnts + (size_t)b * R3;
  for (int v = t; v < R3; v += 256) {
    int d = v >> 8, h = (v >> 4) & 15, w = v & 15;
    A[((d + 1) * 18 + (h + 1)) * 18 + (w + 1)] = sp[v] / fmaxf(cp[v], 1.0f);
  }
  float wa[27];
#pragma unroll
  for (int i = 0; i < 27; ++i) wa[i] = w3a[c * 27 + i];
  float biasa = b3a[c];
  float sa = g3a[c] * rsqrtf(v3a[c] + 1e-4f);
  float ma = m3a[c], bna = be3a[c];
  __syncthreads();
  for (int v = t; v < R3; v += 256) {
    int d = v >> 8, h = (v >> 4) & 15, w = v & 15;
    int base = (d * 18 + h) * 18 + w;
    float s = 0.f;
#pragma unroll
    for (int kd = 0; kd < 3; ++kd)
#pragma unroll
      for (int kh = 0; kh < 3; ++kh)
#pragma unroll
        for (int kw = 0; kw < 3; ++kw)
          s += wa[kd * 9 + kh * 3 + kw] * A[base + kd * 324 + kh * 18 + kw];
    s += biasa;
    s = (s - ma) * sa + bna;
    s = s > 0.f ? s : 0.1f * s;
    Bf[((d + 1) * 18 + (h + 1)) * 18 + (w + 1)] = s;
  }
  float wb[27];
#pragma unroll
  for (int i = 0; i < 27; ++i) wb[i] = w3b[c * 27 + i];
  float biasb = b3b[c];
  float sb = g3b[c] * rsqrtf(v3b[c] + 1e-4f);
  float mb = m3b[c], bnb = be3b[c];
  __syncthreads();
  for (int v = t; v < R3; v += 256) {
    int d = v >> 8, h = (v >> 4) & 15, w = v & 15;
    int base = (d * 18 + h) * 18 + w;
    float s = 0.f;
#pragma unroll
    for (int kd = 0; kd < 3; ++kd)
#pragma unroll
      for (int kh = 0; kh < 3; ++kh)
#pragma unroll
        for (int kw = 0; kw < 3; ++kw)
          s += wb[kd * 9 + kh * 3 + kw] * Bf[base + kd * 324 + kh * 18 + kw];
    s += biasb;
    s = (s - mb) * sb + bnb;
    s = s > 0.f ? s : 0.1f * s;
    gridfT[((size_t)b * R3 + v) * 64 + c] = s;  // voxel-major for coalesced gather
  }
}

// ---------------- K5: trilinear + point branch + output ---------------------
__global__ __launch_bounds__(256) void k_final(
    const float* __restrict__ xT, const float* __restrict__ rec,
    const float* __restrict__ ncT, const float* __restrict__ gridfT,
    const int* __restrict__ idx,
    const float* __restrict__ gp, const float* __restrict__ bp,
    const float* __restrict__ mp, const float* __restrict__ vp,
    const float* __restrict__ wp2,
    const float* __restrict__ gt, const float* __restrict__ bt,
    const float* __restrict__ mt, const float* __restrict__ vt,
    float* __restrict__ out) {
  __shared__ float res[64][17];
  int t = threadIdx.x;
  int c = t & 63, wv = t >> 6;
  int p0 = blockIdx.x * 16;
  int b = p0 / NPTS;  // N % 16 == 0 -> block never straddles batches
  float st = gt[c] * rsqrtf(vt[c] + 1e-5f);
  float mtc = mt[c], btc = bt[c];
  int part = c / 10; if (part > 5) part = 5;
  float sp0 = gp[0] * rsqrtf(vp[0] + 1e-5f);
  float sp1 = gp[1] * rsqrtf(vp[1] + 1e-5f);
  float sp2 = gp[2] * rsqrtf(vp[2] + 1e-5f);
  float mp0 = mp[0], mp1 = mp[1], mp2 = mp[2];
  float bp0 = bp[0], bp1 = bp[1], bp2 = bp[2];
  float w200 = wp2[0], w201 = wp2[1], w202 = wp2[2];
  float w210 = wp2[3], w211 = wp2[4], w212 = wp2[5];
  float w220 = wp2[6], w221 = wp2[7], w222 = wp2[8];
  const float4* rec4 = (const float4*)rec;
  const float4* nc4 = (const float4*)ncT;
  const float* gbase = gridfT + (size_t)b * R3 * 64;

  for (int pi = 0; pi < 4; ++pi) {
    int p = p0 + wv * 4 + pi;
    // trilinear interpolation from grid
    float4 ncv = nc4[p];
    float c0x = floorf(ncv.x), c0y = floorf(ncv.y), c0z = floorf(ncv.z);
    int i0x = (int)c0x, i0y = (int)c0y, i0z = (int)c0z;
    int i1x = min(i0x + 1, 15), i1y = min(i0y + 1, 15), i1z = min(i0z + 1, 15);
    float fx = ncv.x - c0x, fy = ncv.y - c0y, fz = ncv.z - c0z;
    float pv = 0.f;
#pragma unroll
    for (int dx = 0; dx < 2; ++dx)
#pragma unroll
      for (int dy = 0; dy < 2; ++dy)
#pragma unroll
        for (int dz = 0; dz < 2; ++dz) {
          int ix = dx ? i1x : i0x, iy = dy ? i1y : i0y, iz = dz ? i1z : i0z;
          float wg = (dx ? fx : 1.f - fx) * (dy ? fy : 1.f - fy) * (dz ? fz : 1.f - fz);
          pv += wg * gbase[(size_t)((ix * 16 + iy) * 16 + iz) * 64 + c];
        }
    // point branch
    float4 r0 = rec4[(size_t)p * 2], r1 = rec4[(size_t)p * 2 + 1];
    float acc = -1e30f;
    const int* ip = idx + (size_t)p * 16;
#pragma unroll 4
    for (int k = 0; k < 16; ++k) {
      int j = ip[k];
      int pj = b * NPTS + j;
      float4 q0 = rec4[(size_t)pj * 2], q1 = rec4[(size_t)pj * 2 + 1];
      float d0 = q0.x - r0.x, d1 = q0.y - r0.y, d2 = q0.z - r0.z;   // dp1
      float e0 = q0.w - r0.w, e1 = q1.x - r1.x, e2 = q1.y - r1.y;   // wp1*(xj-xn)
      float t0 = fmaxf((e0 - mp0) * sp0 + bp0, 0.f);
      float t1 = fmaxf((e1 - mp1) * sp1 + bp1, 0.f);
      float t2 = fmaxf((e2 - mp2) * sp2 + bp2, 0.f);
      float g0 = w200 * t0 + w201 * t1 + w202 * t2;                  // dp2
      float g1 = w210 * t0 + w211 * t1 + w212 * t2;
      float g2 = w220 * t0 + w221 * t1 + w222 * t2;
      float wsel = part == 0 ? d0 : part == 1 ? d1 : part == 2 ? d2
                 : part == 3 ? g0 : part == 4 ? g1 : g2;
      float xj = xT[(size_t)pj * 64 + c];
      float v = fmaxf((xj * wsel - mtc) * st + btc, 0.f);
      acc = fmaxf(acc, v);
    }
    res[c][wv * 4 + pi] = pv + acc;
  }
  __syncthreads();
  int n0 = p0 % NPTS;
  int i = t & 15, crow = t >> 4;
#pragma unroll
  for (int r2 = 0; r2 < 4; ++r2) {
    int ccw = crow + r2 * 16;
    out[((size_t)b * CC + ccw) * NPTS + n0 + i] = res[ccw][i];
  }
}

extern "C" void kernel_launch(void* const* d_in, const int* in_sizes, int n_in,
                              void* d_out, int out_size, void* d_ws, size_t ws_size,
                              hipStream_t stream) {
  const float* x    = (const float*)d_in[0];
  const float* xyz  = (const float*)d_in[1];
  const int*   idx  = (const int*)d_in[2];
  const float* w3a  = (const float*)d_in[3];
  const float* b3a  = (const float*)d_in[4];
  const float* g3a  = (const float*)d_in[5];
  const float* be3a = (const float*)d_in[6];
  const float* m3a  = (const float*)d_in[7];
  const float* v3a  = (const float*)d_in[8];
  const float* w3b  = (const float*)d_in[9];
  const float* b3b  = (const float*)d_in[10];
  const float* g3b  = (const float*)d_in[11];
  const float* be3b = (const float*)d_in[12];
  const float* m3b  = (const float*)d_in[13];
  const float* v3b  = (const float*)d_in[14];
  const float* wp1  = (const float*)d_in[15];
  const float* gp   = (const float*)d_in[16];
  const float* bp   = (const float*)d_in[17];
  const float* mp   = (const float*)d_in[18];
  const float* vp   = (const float*)d_in[19];
  const float* wp2  = (const float*)d_in[20];
  const float* gt   = (const float*)d_in[21];
  const float* bt   = (const float*)d_in[22];
  const float* mt   = (const float*)d_in[23];
  const float* vt   = (const float*)d_in[24];

  float* ws     = (float*)d_ws;
  float* sums   = ws;                       // B*C*4096       = 524288
  float* cnts   = sums + 524288;            // B*4096         =   8192
  float* meanv  = cnts + 8192;              //                       8
  int*   flat   = (int*)(meanv + 8);        // B*N            =  32768
  float* ncT    = (float*)(flat + 32768);   // B*N*4          = 131072
  float* rec    = ncT + 131072;             // B*N*8          = 262144
  float* xT     = rec + 262144;             // B*N*64         = 2097152
  float* gridfT = xT + 2097152;             // B*4096*64      = 524288

  hipMemsetAsync(sums, 0, (size_t)(524288 + 8192) * sizeof(float), stream);
  k_mean<<<6, 256, 0, stream>>>(xyz, meanv);
  k_voxel<<<(BB * NPTS) / 256, 256, 0, stream>>>(xyz, meanv, cnts, flat, ncT, rec);
  k_transpose<<<(BB * NPTS) / 64, 256, 0, stream>>>(x, flat, wp1, sums, xT, rec);
  k_conv<<<BB * CC, 256, 0, stream>>>(sums, cnts, w3a, b3a, g3a, be3a, m3a, v3a,
                                      w3b, b3b, g3b, be3b, m3b, v3b, gridfT);
  k_final<<<(BB * NPTS) / 16, 256, 0, stream>>>(xT, rec, ncT, gridfT, idx,
                                                gp, bp, mp, vp, wp2,
                                                gt, bt, mt, vt, (float*)d_out);
}

// Round 2
// 162.200 us; speedup vs baseline: 1.7891x; 1.7891x over previous
//
#include <hip/hip_runtime.h>
#include <math.h>

#define BB 2
#define CC 64
#define NPTS 16384
#define KK 16
#define RR 16
#define R3 4096

__device__ __forceinline__ unsigned short f2b(float f) {
  unsigned int u = __float_as_uint(f);
  unsigned int r = u + 0x7fffu + ((u >> 16) & 1u);
  return (unsigned short)(r >> 16);
}
__device__ __forceinline__ float b2f(unsigned short h) {
  return __uint_as_float(((unsigned int)h) << 16);
}

// ---------------- K1: per-(b,axis) mean of xyz ----------------
__global__ void k_mean(const float* __restrict__ xyz, float* __restrict__ meanv) {
  int row = blockIdx.x;  // b*3+o, 6 rows
  const float* src = xyz + (size_t)row * NPTS;
  float s = 0.f;
  for (int i = threadIdx.x; i < NPTS; i += 256) s += src[i];
  for (int off = 32; off; off >>= 1) s += __shfl_down(s, off, 64);
  __shared__ float ls[4];
  int lane = threadIdx.x & 63, wv = threadIdx.x >> 6;
  if (lane == 0) ls[wv] = s;
  __syncthreads();
  if (threadIdx.x == 0) meanv[row] = (ls[0] + ls[1] + ls[2] + ls[3]) / (float)NPTS;
}

// ---------------- K2: voxel coords, flat index, counts, point records -------
__global__ void k_voxel(const float* __restrict__ xyz, const float* __restrict__ meanv,
                        float* __restrict__ cnts, int* __restrict__ flat,
                        float* __restrict__ ncT, float* __restrict__ rec) {
  int p = blockIdx.x * 256 + threadIdx.x;  // 0..B*N
  int b = p / NPTS, n = p % NPTS;
  int vi[3];
#pragma unroll
  for (int o = 0; o < 3; ++o) {
    float v = xyz[((size_t)b * 3 + o) * NPTS + n];
    float t = (v - meanv[b * 3 + o] + 1.0f) * 0.5f * (float)RR;
    t = fminf(fmaxf(t, 0.f), (float)(RR - 1));
    vi[o] = (int)rintf(t);  // jnp.round = round-half-even = rintf
    rec[(size_t)p * 8 + o] = v;
    ncT[(size_t)p * 4 + o] = t;
  }
  ncT[(size_t)p * 4 + 3] = 0.f;
  int f = (vi[0] * RR + vi[1]) * RR + vi[2];
  flat[p] = f;
  atomicAdd(&cnts[b * R3 + f], 1.0f);
}

// ---------------- K3: transpose x -> xTb(B,N,C) bf16, coalesced scatter, y1 -
__global__ __launch_bounds__(256) void k_transpose(
    const float* __restrict__ x, const int* __restrict__ flat,
    const float* __restrict__ wp1, float* __restrict__ sumsVC,
    unsigned short* __restrict__ xTb, float* __restrict__ rec) {
  __shared__ float tile[64][65];
  __shared__ int lflat[64];
  int bi = blockIdx.x;  // 0..B*256
  int b = bi >> 8, n0 = (bi & 255) * 64;
  int t = threadIdx.x;
  int nl = t & 63, cq = t >> 6;  // cq 0..3
  if (t < 64) lflat[t] = flat[b * NPTS + n0 + t];
#pragma unroll 4
  for (int it = 0; it < 16; ++it) {
    int c = it * 4 + cq;
    tile[c][nl] = x[((size_t)b * CC + c) * NPTS + n0 + nl];
  }
  __syncthreads();
  // bf16 transpose write: lanes = channels -> 128B coalesced rows
  int cw = t & 63, nq = t >> 6;
#pragma unroll 4
  for (int it = 0; it < 16; ++it) {
    int n2 = it * 4 + nq;
    xTb[((size_t)(b * NPTS + n0 + n2)) * 64 + cw] = f2b(tile[cw][n2]);
  }
  // voxel scatter: lane = channel, one coalesced 256B atomic row per point
  int wv = t >> 6, lane = t & 63;
#pragma unroll 2
  for (int i = 0; i < 16; ++i) {
    int n2 = wv * 16 + i;
    atomicAdd(&sumsVC[((size_t)b * R3 + lflat[n2]) * 64 + lane], tile[lane][n2]);
  }
  // y1 = wp1 * x : 192 threads, each one 64-length dot
  if (t < 192) {
    int pt = t & 63, o = t >> 6;
    const float* wr = wp1 + o * 64;
    float s = 0.f;
#pragma unroll 8
    for (int c = 0; c < 64; ++c) s += wr[c] * tile[c][pt];
    rec[((size_t)(b * NPTS + n0 + pt)) * 8 + 3 + o] = s;
  }
}

// ---------------- K4: fused depthwise conv x2 + BN + lReLU ------------------
__global__ __launch_bounds__(256) void k_conv(
    const float* __restrict__ sumsVC, const float* __restrict__ cnts,
    const float* __restrict__ w3a, const float* __restrict__ b3a,
    const float* __restrict__ g3a, const float* __restrict__ be3a,
    const float* __restrict__ m3a, const float* __restrict__ v3a,
    const float* __restrict__ w3b, const float* __restrict__ b3b,
    const float* __restrict__ g3b, const float* __restrict__ be3b,
    const float* __restrict__ m3b, const float* __restrict__ v3b,
    unsigned short* __restrict__ gridb) {
  __shared__ float A[5832];   // 18^3 zero-padded
  __shared__ float Bf[5832];
  int bi = blockIdx.x, b = bi >> 6, c = bi & 63;
  int t = threadIdx.x;
  for (int i = t; i < 5832; i += 256) { A[i] = 0.f; Bf[i] = 0.f; }
  __syncthreads();
  const float* cp = cnts + (size_t)b * R3;
  for (int v = t; v < R3; v += 256) {
    int d = v >> 8, h = (v >> 4) & 15, w = v & 15;
    float s = sumsVC[((size_t)b * R3 + v) * 64 + c];
    A[((d + 1) * 18 + (h + 1)) * 18 + (w + 1)] = s / fmaxf(cp[v], 1.0f);
  }
  float wa[27];
#pragma unroll
  for (int i = 0; i < 27; ++i) wa[i] = w3a[c * 27 + i];
  float biasa = b3a[c];
  float sa = g3a[c] * rsqrtf(v3a[c] + 1e-4f);
  float ma = m3a[c], bna = be3a[c];
  __syncthreads();
  for (int v = t; v < R3; v += 256) {
    int d = v >> 8, h = (v >> 4) & 15, w = v & 15;
    int base = (d * 18 + h) * 18 + w;
    float s = 0.f;
#pragma unroll
    for (int kd = 0; kd < 3; ++kd)
#pragma unroll
      for (int kh = 0; kh < 3; ++kh)
#pragma unroll
        for (int kw = 0; kw < 3; ++kw)
          s += wa[kd * 9 + kh * 3 + kw] * A[base + kd * 324 + kh * 18 + kw];
    s += biasa;
    s = (s - ma) * sa + bna;
    s = s > 0.f ? s : 0.1f * s;
    Bf[((d + 1) * 18 + (h + 1)) * 18 + (w + 1)] = s;
  }
  float wb[27];
#pragma unroll
  for (int i = 0; i < 27; ++i) wb[i] = w3b[c * 27 + i];
  float biasb = b3b[c];
  float sb = g3b[c] * rsqrtf(v3b[c] + 1e-4f);
  float mb = m3b[c], bnb = be3b[c];
  __syncthreads();
  for (int v = t; v < R3; v += 256) {
    int d = v >> 8, h = (v >> 4) & 15, w = v & 15;
    int base = (d * 18 + h) * 18 + w;
    float s = 0.f;
#pragma unroll
    for (int kd = 0; kd < 3; ++kd)
#pragma unroll
      for (int kh = 0; kh < 3; ++kh)
#pragma unroll
        for (int kw = 0; kw < 3; ++kw)
          s += wb[kd * 9 + kh * 3 + kw] * Bf[base + kd * 324 + kh * 18 + kw];
    s += biasb;
    s = (s - mb) * sb + bnb;
    s = s > 0.f ? s : 0.1f * s;
    gridb[((size_t)b * R3 + v) * 64 + c] = f2b(s);  // voxel-major bf16
  }
}

// ---------------- K5: trilinear + point branch + output ---------------------
__global__ __launch_bounds__(256) void k_final(
    const unsigned short* __restrict__ xTb, const float* __restrict__ rec,
    const float* __restrict__ ncT, const unsigned short* __restrict__ gridb,
    const int* __restrict__ idx,
    const float* __restrict__ gp, const float* __restrict__ bp,
    const float* __restrict__ mp, const float* __restrict__ vp,
    const float* __restrict__ wp2,
    const float* __restrict__ gt, const float* __restrict__ bt,
    const float* __restrict__ mt, const float* __restrict__ vt,
    float* __restrict__ out) {
  __shared__ float res[64][17];
  int t = threadIdx.x;
  int c = t & 63, wv = t >> 6;
  // XCD-batch swizzle: XCDs 0-3 -> batch 0, XCDs 4-7 -> batch 1.
  int bid = blockIdx.x;
  int xcd = bid & 7;
  int b = xcd >> 2;
  int grp = (bid >> 3) * 4 + (xcd & 3);  // 0..1023 within batch
  int p0 = b * NPTS + grp * 16;
  float st = gt[c] * rsqrtf(vt[c] + 1e-5f);
  float mtc = mt[c], btc = bt[c];
  int part = c / 10; if (part > 5) part = 5;
  float sp0 = gp[0] * rsqrtf(vp[0] + 1e-5f);
  float sp1 = gp[1] * rsqrtf(vp[1] + 1e-5f);
  float sp2 = gp[2] * rsqrtf(vp[2] + 1e-5f);
  float mp0 = mp[0], mp1 = mp[1], mp2 = mp[2];
  float bp0 = bp[0], bp1 = bp[1], bp2 = bp[2];
  float w200 = wp2[0], w201 = wp2[1], w202 = wp2[2];
  float w210 = wp2[3], w211 = wp2[4], w212 = wp2[5];
  float w220 = wp2[6], w221 = wp2[7], w222 = wp2[8];
  const float4* rec4 = (const float4*)rec;
  const float4* nc4 = (const float4*)ncT;
  const unsigned short* gbase = gridb + (size_t)b * R3 * 64;

#pragma unroll 2
  for (int pi = 0; pi < 4; ++pi) {
    int p = p0 + wv * 4 + pi;
    // trilinear interpolation from grid (bf16 rows, 128B coalesced)
    float4 ncv = nc4[p];
    float c0x = floorf(ncv.x), c0y = floorf(ncv.y), c0z = floorf(ncv.z);
    int i0x = (int)c0x, i0y = (int)c0y, i0z = (int)c0z;
    int i1x = min(i0x + 1, 15), i1y = min(i0y + 1, 15), i1z = min(i0z + 1, 15);
    float fx = ncv.x - c0x, fy = ncv.y - c0y, fz = ncv.z - c0z;
    float pv = 0.f;
#pragma unroll
    for (int dx = 0; dx < 2; ++dx)
#pragma unroll
      for (int dy = 0; dy < 2; ++dy)
#pragma unroll
        for (int dz = 0; dz < 2; ++dz) {
          int ix = dx ? i1x : i0x, iy = dy ? i1y : i0y, iz = dz ? i1z : i0z;
          float wg = (dx ? fx : 1.f - fx) * (dy ? fy : 1.f - fy) * (dz ? fz : 1.f - fz);
          pv += wg * b2f(gbase[(size_t)((ix * 16 + iy) * 16 + iz) * 64 + c]);
        }
    // point branch
    float4 r0 = rec4[(size_t)p * 2], r1 = rec4[(size_t)p * 2 + 1];
    float acc = -1e30f;
    const int4* ip4 = (const int4*)(idx + (size_t)p * 16);
    int4 iv0 = ip4[0], iv1 = ip4[1], iv2 = ip4[2], iv3 = ip4[3];
    int js[16] = {iv0.x, iv0.y, iv0.z, iv0.w, iv1.x, iv1.y, iv1.z, iv1.w,
                  iv2.x, iv2.y, iv2.z, iv2.w, iv3.x, iv3.y, iv3.z, iv3.w};
#pragma unroll 4
    for (int k = 0; k < 16; ++k) {
      int pj = b * NPTS + js[k];
      float4 q0 = rec4[(size_t)pj * 2], q1 = rec4[(size_t)pj * 2 + 1];
      float d0 = q0.x - r0.x, d1 = q0.y - r0.y, d2 = q0.z - r0.z;   // dp1
      float e0 = q0.w - r0.w, e1 = q1.x - r1.x, e2 = q1.y - r1.y;   // wp1*(xj-xn)
      float t0 = fmaxf((e0 - mp0) * sp0 + bp0, 0.f);
      float t1 = fmaxf((e1 - mp1) * sp1 + bp1, 0.f);
      float t2 = fmaxf((e2 - mp2) * sp2 + bp2, 0.f);
      float g0 = w200 * t0 + w201 * t1 + w202 * t2;                  // dp2
      float g1 = w210 * t0 + w211 * t1 + w212 * t2;
      float g2 = w220 * t0 + w221 * t1 + w222 * t2;
      float wsel = part == 0 ? d0 : part == 1 ? d1 : part == 2 ? d2
                 : part == 3 ? g0 : part == 4 ? g1 : g2;
      float xj = b2f(xTb[(size_t)pj * 64 + c]);
      float v = fmaxf((xj * wsel - mtc) * st + btc, 0.f);
      acc = fmaxf(acc, v);
    }
    res[c][wv * 4 + pi] = pv + acc;
  }
  __syncthreads();
  int n0 = grp * 16;
  int i = t & 15, crow = t >> 4;
#pragma unroll
  for (int r2 = 0; r2 < 4; ++r2) {
    int ccw = crow + r2 * 16;
    out[((size_t)b * CC + ccw) * NPTS + n0 + i] = res[ccw][i];
  }
}

extern "C" void kernel_launch(void* const* d_in, const int* in_sizes, int n_in,
                              void* d_out, int out_size, void* d_ws, size_t ws_size,
                              hipStream_t stream) {
  const float* x    = (const float*)d_in[0];
  const float* xyz  = (const float*)d_in[1];
  const int*   idx  = (const int*)d_in[2];
  const float* w3a  = (const float*)d_in[3];
  const float* b3a  = (const float*)d_in[4];
  const float* g3a  = (const float*)d_in[5];
  const float* be3a = (const float*)d_in[6];
  const float* m3a  = (const float*)d_in[7];
  const float* v3a  = (const float*)d_in[8];
  const float* w3b  = (const float*)d_in[9];
  const float* b3b  = (const float*)d_in[10];
  const float* g3b  = (const float*)d_in[11];
  const float* be3b = (const float*)d_in[12];
  const float* m3b  = (const float*)d_in[13];
  const float* v3b  = (const float*)d_in[14];
  const float* wp1  = (const float*)d_in[15];
  const float* gp   = (const float*)d_in[16];
  const float* bp   = (const float*)d_in[17];
  const float* mp   = (const float*)d_in[18];
  const float* vp   = (const float*)d_in[19];
  const float* wp2  = (const float*)d_in[20];
  const float* gt   = (const float*)d_in[21];
  const float* bt   = (const float*)d_in[22];
  const float* mt   = (const float*)d_in[23];
  const float* vt   = (const float*)d_in[24];

  float* ws     = (float*)d_ws;
  float* sumsVC = ws;                          // B*4096*64      = 524288 f32
  float* cnts   = sumsVC + 524288;             // B*4096         =   8192
  float* meanv  = cnts + 8192;                 //                       8
  int*   flat   = (int*)(meanv + 8);           // B*N            =  32768
  float* ncT    = (float*)(flat + 32768);      // B*N*4          = 131072
  float* rec    = ncT + 131072;                // B*N*8          = 262144
  unsigned short* xTb   = (unsigned short*)(rec + 262144);  // B*N*64 bf16
  unsigned short* gridb = xTb + 2097152;                    // B*4096*64 bf16

  hipMemsetAsync(sumsVC, 0, (size_t)(524288 + 8192) * sizeof(float), stream);
  k_mean<<<6, 256, 0, stream>>>(xyz, meanv);
  k_voxel<<<(BB * NPTS) / 256, 256, 0, stream>>>(xyz, meanv, cnts, flat, ncT, rec);
  k_transpose<<<(BB * NPTS) / 64, 256, 0, stream>>>(x, flat, wp1, sumsVC, xTb, rec);
  k_conv<<<BB * CC, 256, 0, stream>>>(sumsVC, cnts, w3a, b3a, g3a, be3a, m3a, v3a,
                                      w3b, b3b, g3b, be3b, m3b, v3b, gridb);
  k_final<<<(BB * NPTS) / 16, 256, 0, stream>>>(xTb, rec, ncT, gridb, idx,
                                                gp, bp, mp, vp, wp2,
                                                gt, bt, mt, vt, (float*)d_out);
}

// Round 3
// 78.916 us; speedup vs baseline: 3.6772x; 2.0554x over previous
//
#include <hip/hip_runtime.h>
#include <math.h>

#define BB 2
#define CC 64
#define NPTS 16384
#define KK 16
#define RR 16
#define R3 4096

__device__ __forceinline__ unsigned short f2b(float f) {
  unsigned int u = __float_as_uint(f);
  unsigned int r = u + 0x7fffu + ((u >> 16) & 1u);
  return (unsigned short)(r >> 16);
}
__device__ __forceinline__ float b2f(unsigned short h) {
  return __uint_as_float(((unsigned int)h) << 16);
}

// ---------------- K1: per-(b,axis) mean of xyz ----------------
__global__ void k_mean(const float* __restrict__ xyz, float* __restrict__ meanv) {
  int row = blockIdx.x;  // b*3+o, 6 rows
  const float* src = xyz + (size_t)row * NPTS;
  float s = 0.f;
  for (int i = threadIdx.x; i < NPTS; i += 256) s += src[i];
  for (int off = 32; off; off >>= 1) s += __shfl_down(s, off, 64);
  __shared__ float ls[4];
  int lane = threadIdx.x & 63, wv = threadIdx.x >> 6;
  if (lane == 0) ls[wv] = s;
  __syncthreads();
  if (threadIdx.x == 0) meanv[row] = (ls[0] + ls[1] + ls[2] + ls[3]) / (float)NPTS;
}

// ---------------- K2: voxel coords, flat index, counts, point records -------
__global__ void k_voxel(const float* __restrict__ xyz, const float* __restrict__ meanv,
                        float* __restrict__ cnts, int* __restrict__ flat,
                        float* __restrict__ ncT, float* __restrict__ rec) {
  int p = blockIdx.x * 256 + threadIdx.x;  // 0..B*N
  int b = p / NPTS, n = p % NPTS;
  int vi[3];
#pragma unroll
  for (int o = 0; o < 3; ++o) {
    float v = xyz[((size_t)b * 3 + o) * NPTS + n];
    float t = (v - meanv[b * 3 + o] + 1.0f) * 0.5f * (float)RR;
    t = fminf(fmaxf(t, 0.f), (float)(RR - 1));
    vi[o] = (int)rintf(t);  // jnp.round = round-half-even = rintf
    rec[(size_t)p * 8 + o] = v;
    ncT[(size_t)p * 4 + o] = t;
  }
  ncT[(size_t)p * 4 + 3] = 0.f;
  int f = (vi[0] * RR + vi[1]) * RR + vi[2];
  flat[p] = f;
  atomicAdd(&cnts[b * R3 + f], 1.0f);
}

// ---------------- K3: transpose x -> xTb(B,N,C) bf16, coalesced scatter, y1 -
__global__ __launch_bounds__(256) void k_transpose(
    const float* __restrict__ x, const int* __restrict__ flat,
    const float* __restrict__ wp1, float* __restrict__ sumsVC,
    unsigned short* __restrict__ xTb, float* __restrict__ rec) {
  __shared__ float tile[64][65];
  __shared__ int lflat[64];
  int bi = blockIdx.x;  // 0..B*256
  int b = bi >> 8, n0 = (bi & 255) * 64;
  int t = threadIdx.x;
  int nl = t & 63, cq = t >> 6;  // cq 0..3
  if (t < 64) lflat[t] = flat[b * NPTS + n0 + t];
#pragma unroll 4
  for (int it = 0; it < 16; ++it) {
    int c = it * 4 + cq;
    tile[c][nl] = x[((size_t)b * CC + c) * NPTS + n0 + nl];
  }
  __syncthreads();
  // bf16 transpose write: lanes = channels -> 128B coalesced rows
  int cw = t & 63, nq = t >> 6;
#pragma unroll 4
  for (int it = 0; it < 16; ++it) {
    int n2 = it * 4 + nq;
    xTb[((size_t)(b * NPTS + n0 + n2)) * 64 + cw] = f2b(tile[cw][n2]);
  }
  // voxel scatter: lane = channel, one coalesced 256B atomic row per point
  int wv = t >> 6, lane = t & 63;
#pragma unroll 2
  for (int i = 0; i < 16; ++i) {
    int n2 = wv * 16 + i;
    atomicAdd(&sumsVC[((size_t)b * R3 + lflat[n2]) * 64 + lane], tile[lane][n2]);
  }
  // y1 = wp1 * x : 192 threads, each one 64-length dot
  if (t < 192) {
    int pt = t & 63, o = t >> 6;
    const float* wr = wp1 + o * 64;
    float s = 0.f;
#pragma unroll 8
    for (int c = 0; c < 64; ++c) s += wr[c] * tile[c][pt];
    rec[((size_t)(b * NPTS + n0 + pt)) * 8 + 3 + o] = s;
  }
}

// ---------------- K4: fused depthwise conv x2 + BN + lReLU ------------------
__global__ __launch_bounds__(256) void k_conv(
    const float* __restrict__ sumsVC, const float* __restrict__ cnts,
    const float* __restrict__ w3a, const float* __restrict__ b3a,
    const float* __restrict__ g3a, const float* __restrict__ be3a,
    const float* __restrict__ m3a, const float* __restrict__ v3a,
    const float* __restrict__ w3b, const float* __restrict__ b3b,
    const float* __restrict__ g3b, const float* __restrict__ be3b,
    const float* __restrict__ m3b, const float* __restrict__ v3b,
    unsigned short* __restrict__ gridb) {
  __shared__ float A[5832];   // 18^3 zero-padded
  __shared__ float Bf[5832];
  int bi = blockIdx.x, b = bi >> 6, c = bi & 63;
  int t = threadIdx.x;
  for (int i = t; i < 5832; i += 256) { A[i] = 0.f; Bf[i] = 0.f; }
  __syncthreads();
  const float* cp = cnts + (size_t)b * R3;
  for (int v = t; v < R3; v += 256) {
    int d = v >> 8, h = (v >> 4) & 15, w = v & 15;
    float s = sumsVC[((size_t)b * R3 + v) * 64 + c];
    A[((d + 1) * 18 + (h + 1)) * 18 + (w + 1)] = s / fmaxf(cp[v], 1.0f);
  }
  float wa[27];
#pragma unroll
  for (int i = 0; i < 27; ++i) wa[i] = w3a[c * 27 + i];
  float biasa = b3a[c];
  float sa = g3a[c] * rsqrtf(v3a[c] + 1e-4f);
  float ma = m3a[c], bna = be3a[c];
  __syncthreads();
  for (int v = t; v < R3; v += 256) {
    int d = v >> 8, h = (v >> 4) & 15, w = v & 15;
    int base = (d * 18 + h) * 18 + w;
    float s = 0.f;
#pragma unroll
    for (int kd = 0; kd < 3; ++kd)
#pragma unroll
      for (int kh = 0; kh < 3; ++kh)
#pragma unroll
        for (int kw = 0; kw < 3; ++kw)
          s += wa[kd * 9 + kh * 3 + kw] * A[base + kd * 324 + kh * 18 + kw];
    s += biasa;
    s = (s - ma) * sa + bna;
    s = s > 0.f ? s : 0.1f * s;
    Bf[((d + 1) * 18 + (h + 1)) * 18 + (w + 1)] = s;
  }
  float wb[27];
#pragma unroll
  for (int i = 0; i < 27; ++i) wb[i] = w3b[c * 27 + i];
  float biasb = b3b[c];
  float sb = g3b[c] * rsqrtf(v3b[c] + 1e-4f);
  float mb = m3b[c], bnb = be3b[c];
  __syncthreads();
  for (int v = t; v < R3; v += 256) {
    int d = v >> 8, h = (v >> 4) & 15, w = v & 15;
    int base = (d * 18 + h) * 18 + w;
    float s = 0.f;
#pragma unroll
    for (int kd = 0; kd < 3; ++kd)
#pragma unroll
      for (int kh = 0; kh < 3; ++kh)
#pragma unroll
        for (int kw = 0; kw < 3; ++kw)
          s += wb[kd * 9 + kh * 3 + kw] * Bf[base + kd * 324 + kh * 18 + kw];
    s += biasb;
    s = (s - mb) * sb + bnb;
    s = s > 0.f ? s : 0.1f * s;
    gridb[((size_t)b * R3 + v) * 64 + c] = f2b(s);  // voxel-major bf16
  }
}

// ---------------- K5: trilinear + point branch + output ---------------------
// Phase 1: one thread per (point,k) computes the 6 candidate weights once.
// Phase 2: per wave, unrolled k-loop of coalesced xTb gathers + LDS weights.
__global__ __launch_bounds__(256) void k_final(
    const unsigned short* __restrict__ xTb, const float* __restrict__ rec,
    const float* __restrict__ ncT, const unsigned short* __restrict__ gridb,
    const int* __restrict__ idx,
    const float* __restrict__ gp, const float* __restrict__ bp,
    const float* __restrict__ mp, const float* __restrict__ vp,
    const float* __restrict__ wp2,
    const float* __restrict__ gt, const float* __restrict__ bt,
    const float* __restrict__ mt, const float* __restrict__ vt,
    float* __restrict__ out) {
  __shared__ float wgt[16 * 16 * 7];  // [p][k][7]: 0-5 = weights, 6 = j bits
  __shared__ float res[64][17];
  int t = threadIdx.x;
  int c = t & 63, wv = t >> 6;
  // XCD-batch swizzle: XCDs 0-3 -> batch 0, XCDs 4-7 -> batch 1.
  int bid = blockIdx.x;
  int xcd = bid & 7;
  int b = xcd >> 2;
  int grp = (bid >> 3) * 4 + (xcd & 3);  // 0..1023 within batch
  int p0 = b * NPTS + grp * 16;
  int bBase = b * NPTS;
  const float4* rec4 = (const float4*)rec;

  // ---- phase 1 ----
  {
    int pl = t >> 4, k = t & 15;
    int p = p0 + pl;
    int j = idx[(size_t)p * 16 + k];
    float4 r0 = rec4[(size_t)p * 2], r1 = rec4[(size_t)p * 2 + 1];
    int pj = bBase + j;
    float4 q0 = rec4[(size_t)pj * 2], q1 = rec4[(size_t)pj * 2 + 1];
    float sp0 = gp[0] * rsqrtf(vp[0] + 1e-5f);
    float sp1 = gp[1] * rsqrtf(vp[1] + 1e-5f);
    float sp2 = gp[2] * rsqrtf(vp[2] + 1e-5f);
    float d0 = q0.x - r0.x, d1 = q0.y - r0.y, d2 = q0.z - r0.z;  // dp1
    float e0 = q0.w - r0.w, e1 = q1.x - r1.x, e2 = q1.y - r1.y;  // wp1*(xj-xn)
    float t0 = fmaxf((e0 - mp[0]) * sp0 + bp[0], 0.f);
    float t1 = fmaxf((e1 - mp[1]) * sp1 + bp[1], 0.f);
    float t2 = fmaxf((e2 - mp[2]) * sp2 + bp[2], 0.f);
    float* wp = &wgt[(pl * 16 + k) * 7];
    wp[0] = d0; wp[1] = d1; wp[2] = d2;
    wp[3] = wp2[0] * t0 + wp2[1] * t1 + wp2[2] * t2;
    wp[4] = wp2[3] * t0 + wp2[4] * t1 + wp2[5] * t2;
    wp[5] = wp2[6] * t0 + wp2[7] * t1 + wp2[8] * t2;
    ((int*)wp)[6] = j;
  }

  float st = gt[c] * rsqrtf(vt[c] + 1e-5f);
  float mtc = mt[c], btc = bt[c];
  int part = c / 10; if (part > 5) part = 5;
  const float4* nc4 = (const float4*)ncT;
  const unsigned short* gbase = gridb + (size_t)b * R3 * 64;
  __syncthreads();

  // ---- phase 2 ----
#pragma unroll
  for (int pi = 0; pi < 4; ++pi) {
    int pl = wv * 4 + pi;
    int p = p0 + pl;
    // trilinear interpolation from grid (bf16 rows, 128B coalesced)
    float4 ncv = nc4[p];
    float c0x = floorf(ncv.x), c0y = floorf(ncv.y), c0z = floorf(ncv.z);
    int i0x = (int)c0x, i0y = (int)c0y, i0z = (int)c0z;
    int i1x = min(i0x + 1, 15), i1y = min(i0y + 1, 15), i1z = min(i0z + 1, 15);
    float fx = ncv.x - c0x, fy = ncv.y - c0y, fz = ncv.z - c0z;
    float pv = 0.f;
#pragma unroll
    for (int dx = 0; dx < 2; ++dx)
#pragma unroll
      for (int dy = 0; dy < 2; ++dy)
#pragma unroll
        for (int dz = 0; dz < 2; ++dz) {
          int ix = dx ? i1x : i0x, iy = dy ? i1y : i0y, iz = dz ? i1z : i0z;
          float wg = (dx ? fx : 1.f - fx) * (dy ? fy : 1.f - fy) * (dz ? fz : 1.f - fz);
          pv += wg * b2f(gbase[(size_t)((ix * 16 + iy) * 16 + iz) * 64 + c]);
        }
    // point branch: j + weight from LDS, 16 independent coalesced gathers
    const float* wrow = &wgt[pl * 16 * 7];
    int jv[16];
#pragma unroll
    for (int k = 0; k < 16; ++k) jv[k] = ((const int*)wrow)[k * 7 + 6];
    unsigned short xv[16];
#pragma unroll
    for (int k = 0; k < 16; ++k) xv[k] = xTb[((size_t)(bBase + jv[k])) * 64 + c];
    float acc = -1e30f;
#pragma unroll
    for (int k = 0; k < 16; ++k) {
      float w = wrow[k * 7 + part];
      float v = fmaxf((b2f(xv[k]) * w - mtc) * st + btc, 0.f);
      acc = fmaxf(acc, v);
    }
    res[c][pl] = pv + acc;
  }
  __syncthreads();
  int n0 = grp * 16;
  int i = t & 15, crow = t >> 4;
#pragma unroll
  for (int r2 = 0; r2 < 4; ++r2) {
    int ccw = crow + r2 * 16;
    out[((size_t)b * CC + ccw) * NPTS + n0 + i] = res[ccw][i];
  }
}

extern "C" void kernel_launch(void* const* d_in, const int* in_sizes, int n_in,
                              void* d_out, int out_size, void* d_ws, size_t ws_size,
                              hipStream_t stream) {
  const float* x    = (const float*)d_in[0];
  const float* xyz  = (const float*)d_in[1];
  const int*   idx  = (const int*)d_in[2];
  const float* w3a  = (const float*)d_in[3];
  const float* b3a  = (const float*)d_in[4];
  const float* g3a  = (const float*)d_in[5];
  const float* be3a = (const float*)d_in[6];
  const float* m3a  = (const float*)d_in[7];
  const float* v3a  = (const float*)d_in[8];
  const float* w3b  = (const float*)d_in[9];
  const float* b3b  = (const float*)d_in[10];
  const float* g3b  = (const float*)d_in[11];
  const float* be3b = (const float*)d_in[12];
  const float* m3b  = (const float*)d_in[13];
  const float* v3b  = (const float*)d_in[14];
  const float* wp1  = (const float*)d_in[15];
  const float* gp   = (const float*)d_in[16];
  const float* bp   = (const float*)d_in[17];
  const float* mp   = (const float*)d_in[18];
  const float* vp   = (const float*)d_in[19];
  const float* wp2  = (const float*)d_in[20];
  const float* gt   = (const float*)d_in[21];
  const float* bt   = (const float*)d_in[22];
  const float* mt   = (const float*)d_in[23];
  const float* vt   = (const float*)d_in[24];

  float* ws     = (float*)d_ws;
  float* sumsVC = ws;                          // B*4096*64      = 524288 f32
  float* cnts   = sumsVC + 524288;             // B*4096         =   8192
  float* meanv  = cnts + 8192;                 //                       8
  int*   flat   = (int*)(meanv + 8);           // B*N            =  32768
  float* ncT    = (float*)(flat + 32768);      // B*N*4          = 131072
  float* rec    = ncT + 131072;                // B*N*8          = 262144
  unsigned short* xTb   = (unsigned short*)(rec + 262144);  // B*N*64 bf16
  unsigned short* gridb = xTb + 2097152;                    // B*4096*64 bf16

  hipMemsetAsync(sumsVC, 0, (size_t)(524288 + 8192) * sizeof(float), stream);
  k_mean<<<6, 256, 0, stream>>>(xyz, meanv);
  k_voxel<<<(BB * NPTS) / 256, 256, 0, stream>>>(xyz, meanv, cnts, flat, ncT, rec);
  k_transpose<<<(BB * NPTS) / 64, 256, 0, stream>>>(x, flat, wp1, sumsVC, xTb, rec);
  k_conv<<<BB * CC, 256, 0, stream>>>(sumsVC, cnts, w3a, b3a, g3a, be3a, m3a, v3a,
                                      w3b, b3b, g3b, be3b, m3b, v3b, gridb);
  k_final<<<(BB * NPTS) / 16, 256, 0, stream>>>(xTb, rec, ncT, gridb, idx,
                                                gp, bp, mp, vp, wp2,
                                                gt, bt, mt, vt, (float*)d_out);
}

// Round 4
// 74.619 us; speedup vs baseline: 3.8889x; 1.0576x over previous
//
#include <hip/hip_runtime.h>
#include <math.h>

#define BB 2
#define CC 64
#define NPTS 16384
#define KK 16
#define RR 16
#define R3 4096

__device__ __forceinline__ unsigned short f2b(float f) {
  unsigned int u = __float_as_uint(f);
  unsigned int r = u + 0x7fffu + ((u >> 16) & 1u);
  return (unsigned short)(r >> 16);
}
__device__ __forceinline__ float b2f(unsigned short h) {
  return __uint_as_float(((unsigned int)h) << 16);
}

// ---------------- K1: zero scratch (all blocks) + per-(b,axis) mean (blocks 0-5)
__global__ __launch_bounds__(256) void k_mean(const float* __restrict__ xyz,
                                              float* __restrict__ meanv,
                                              float4* __restrict__ zbase,
                                              int zcount4) {
  // grid-stride float4 zeroing of sumsVC + cnts (2.13 MB)
  int gt = blockIdx.x * 256 + threadIdx.x;
  int stride = gridDim.x * 256;
  for (int i = gt; i < zcount4; i += stride)
    zbase[i] = make_float4(0.f, 0.f, 0.f, 0.f);

  if (blockIdx.x < 6) {
    int row = blockIdx.x;  // b*3+o
    const float* src = xyz + (size_t)row * NPTS;
    float s = 0.f;
    for (int i = threadIdx.x; i < NPTS; i += 256) s += src[i];
    for (int off = 32; off; off >>= 1) s += __shfl_down(s, off, 64);
    __shared__ float ls[4];
    int lane = threadIdx.x & 63, wv = threadIdx.x >> 6;
    if (lane == 0) ls[wv] = s;
    __syncthreads();
    if (threadIdx.x == 0) meanv[row] = (ls[0] + ls[1] + ls[2] + ls[3]) / (float)NPTS;
  }
}

// ---------------- K2: voxel coords, flat index, counts, point records -------
__global__ void k_voxel(const float* __restrict__ xyz, const float* __restrict__ meanv,
                        float* __restrict__ cnts, int* __restrict__ flat,
                        float* __restrict__ ncT, float* __restrict__ rec) {
  int p = blockIdx.x * 256 + threadIdx.x;  // 0..B*N
  int b = p / NPTS, n = p % NPTS;
  int vi[3];
#pragma unroll
  for (int o = 0; o < 3; ++o) {
    float v = xyz[((size_t)b * 3 + o) * NPTS + n];
    float t = (v - meanv[b * 3 + o] + 1.0f) * 0.5f * (float)RR;
    t = fminf(fmaxf(t, 0.f), (float)(RR - 1));
    vi[o] = (int)rintf(t);  // jnp.round = round-half-even = rintf
    rec[(size_t)p * 8 + o] = v;
    ncT[(size_t)p * 4 + o] = t;
  }
  ncT[(size_t)p * 4 + 3] = 0.f;
  int f = (vi[0] * RR + vi[1]) * RR + vi[2];
  flat[p] = f;
  atomicAdd(&cnts[b * R3 + f], 1.0f);
}

// ---------------- K3: transpose x -> xTb(B,N,C) bf16, coalesced scatter, y1 -
__global__ __launch_bounds__(256) void k_transpose(
    const float* __restrict__ x, const int* __restrict__ flat,
    const float* __restrict__ wp1, float* __restrict__ sumsVC,
    unsigned short* __restrict__ xTb, float* __restrict__ rec) {
  __shared__ float tile[64][65];
  __shared__ int lflat[64];
  int bi = blockIdx.x;  // 0..B*256
  int b = bi >> 8, n0 = (bi & 255) * 64;
  int t = threadIdx.x;
  int nl = t & 63, cq = t >> 6;  // cq 0..3
  if (t < 64) lflat[t] = flat[b * NPTS + n0 + t];
#pragma unroll 4
  for (int it = 0; it < 16; ++it) {
    int c = it * 4 + cq;
    tile[c][nl] = x[((size_t)b * CC + c) * NPTS + n0 + nl];
  }
  __syncthreads();
  // bf16 transpose write: lanes = channels -> 128B coalesced rows
  int cw = t & 63, nq = t >> 6;
#pragma unroll 4
  for (int it = 0; it < 16; ++it) {
    int n2 = it * 4 + nq;
    xTb[((size_t)(b * NPTS + n0 + n2)) * 64 + cw] = f2b(tile[cw][n2]);
  }
  // voxel scatter: lane = channel, one coalesced 256B atomic row per point
  int wv = t >> 6, lane = t & 63;
#pragma unroll 2
  for (int i = 0; i < 16; ++i) {
    int n2 = wv * 16 + i;
    atomicAdd(&sumsVC[((size_t)b * R3 + lflat[n2]) * 64 + lane], tile[lane][n2]);
  }
  // y1 = wp1 * x : 192 threads, each one 64-length dot
  if (t < 192) {
    int pt = t & 63, o = t >> 6;
    const float* wr = wp1 + o * 64;
    float s = 0.f;
#pragma unroll 8
    for (int c = 0; c < 64; ++c) s += wr[c] * tile[c][pt];
    rec[((size_t)(b * NPTS + n0 + pt)) * 8 + 3 + o] = s;
  }
}

// ---------------- K4: fused depthwise conv x2 + BN + lReLU ------------------
__global__ __launch_bounds__(256) void k_conv(
    const float* __restrict__ sumsVC, const float* __restrict__ cnts,
    const float* __restrict__ w3a, const float* __restrict__ b3a,
    const float* __restrict__ g3a, const float* __restrict__ be3a,
    const float* __restrict__ m3a, const float* __restrict__ v3a,
    const float* __restrict__ w3b, const float* __restrict__ b3b,
    const float* __restrict__ g3b, const float* __restrict__ be3b,
    const float* __restrict__ m3b, const float* __restrict__ v3b,
    unsigned short* __restrict__ gridb) {
  __shared__ float A[5832];   // 18^3 zero-padded
  __shared__ float Bf[5832];
  int bi = blockIdx.x, b = bi >> 6, c = bi & 63;
  int t = threadIdx.x;
  for (int i = t; i < 5832; i += 256) { A[i] = 0.f; Bf[i] = 0.f; }
  __syncthreads();
  const float* cp = cnts + (size_t)b * R3;
  for (int v = t; v < R3; v += 256) {
    int d = v >> 8, h = (v >> 4) & 15, w = v & 15;
    float s = sumsVC[((size_t)b * R3 + v) * 64 + c];
    A[((d + 1) * 18 + (h + 1)) * 18 + (w + 1)] = s / fmaxf(cp[v], 1.0f);
  }
  float wa[27];
#pragma unroll
  for (int i = 0; i < 27; ++i) wa[i] = w3a[c * 27 + i];
  float biasa = b3a[c];
  float sa = g3a[c] * rsqrtf(v3a[c] + 1e-4f);
  float ma = m3a[c], bna = be3a[c];
  __syncthreads();
  for (int v = t; v < R3; v += 256) {
    int d = v >> 8, h = (v >> 4) & 15, w = v & 15;
    int base = (d * 18 + h) * 18 + w;
    float s = 0.f;
#pragma unroll
    for (int kd = 0; kd < 3; ++kd)
#pragma unroll
      for (int kh = 0; kh < 3; ++kh)
#pragma unroll
        for (int kw = 0; kw < 3; ++kw)
          s += wa[kd * 9 + kh * 3 + kw] * A[base + kd * 324 + kh * 18 + kw];
    s += biasa;
    s = (s - ma) * sa + bna;
    s = s > 0.f ? s : 0.1f * s;
    Bf[((d + 1) * 18 + (h + 1)) * 18 + (w + 1)] = s;
  }
  float wb[27];
#pragma unroll
  for (int i = 0; i < 27; ++i) wb[i] = w3b[c * 27 + i];
  float biasb = b3b[c];
  float sb = g3b[c] * rsqrtf(v3b[c] + 1e-4f);
  float mb = m3b[c], bnb = be3b[c];
  __syncthreads();
  for (int v = t; v < R3; v += 256) {
    int d = v >> 8, h = (v >> 4) & 15, w = v & 15;
    int base = (d * 18 + h) * 18 + w;
    float s = 0.f;
#pragma unroll
    for (int kd = 0; kd < 3; ++kd)
#pragma unroll
      for (int kh = 0; kh < 3; ++kh)
#pragma unroll
        for (int kw = 0; kw < 3; ++kw)
          s += wb[kd * 9 + kh * 3 + kw] * Bf[base + kd * 324 + kh * 18 + kw];
    s += biasb;
    s = (s - mb) * sb + bnb;
    s = s > 0.f ? s : 0.1f * s;
    gridb[((size_t)b * R3 + v) * 64 + c] = f2b(s);  // voxel-major bf16
  }
}

// ---------------- K5: trilinear + point branch + output ---------------------
// Phase 1: one thread per (point,k) computes the 6 candidate weights once.
// Phase 2: per wave, unrolled k-loop of coalesced xTb gathers + LDS weights.
__global__ __launch_bounds__(256) void k_final(
    const unsigned short* __restrict__ xTb, const float* __restrict__ rec,
    const float* __restrict__ ncT, const unsigned short* __restrict__ gridb,
    const int* __restrict__ idx,
    const float* __restrict__ gp, const float* __restrict__ bp,
    const float* __restrict__ mp, const float* __restrict__ vp,
    const float* __restrict__ wp2,
    const float* __restrict__ gt, const float* __restrict__ bt,
    const float* __restrict__ mt, const float* __restrict__ vt,
    float* __restrict__ out) {
  __shared__ float wgt[16 * 16 * 7];  // [p][k][7]: 0-5 = weights, 6 = j bits
  __shared__ float res[64][17];
  int t = threadIdx.x;
  int c = t & 63, wv = t >> 6;
  // XCD-batch swizzle: XCDs 0-3 -> batch 0, XCDs 4-7 -> batch 1.
  int bid = blockIdx.x;
  int xcd = bid & 7;
  int b = xcd >> 2;
  int grp = (bid >> 3) * 4 + (xcd & 3);  // 0..1023 within batch
  int p0 = b * NPTS + grp * 16;
  int bBase = b * NPTS;
  const float4* rec4 = (const float4*)rec;

  // ---- phase 1 ----
  {
    int pl = t >> 4, k = t & 15;
    int p = p0 + pl;
    int j = idx[(size_t)p * 16 + k];
    float4 r0 = rec4[(size_t)p * 2], r1 = rec4[(size_t)p * 2 + 1];
    int pj = bBase + j;
    float4 q0 = rec4[(size_t)pj * 2], q1 = rec4[(size_t)pj * 2 + 1];
    float sp0 = gp[0] * rsqrtf(vp[0] + 1e-5f);
    float sp1 = gp[1] * rsqrtf(vp[1] + 1e-5f);
    float sp2 = gp[2] * rsqrtf(vp[2] + 1e-5f);
    float d0 = q0.x - r0.x, d1 = q0.y - r0.y, d2 = q0.z - r0.z;  // dp1
    float e0 = q0.w - r0.w, e1 = q1.x - r1.x, e2 = q1.y - r1.y;  // wp1*(xj-xn)
    float t0 = fmaxf((e0 - mp[0]) * sp0 + bp[0], 0.f);
    float t1 = fmaxf((e1 - mp[1]) * sp1 + bp[1], 0.f);
    float t2 = fmaxf((e2 - mp[2]) * sp2 + bp[2], 0.f);
    float* wp = &wgt[(pl * 16 + k) * 7];
    wp[0] = d0; wp[1] = d1; wp[2] = d2;
    wp[3] = wp2[0] * t0 + wp2[1] * t1 + wp2[2] * t2;
    wp[4] = wp2[3] * t0 + wp2[4] * t1 + wp2[5] * t2;
    wp[5] = wp2[6] * t0 + wp2[7] * t1 + wp2[8] * t2;
    ((int*)wp)[6] = j;
  }

  float st = gt[c] * rsqrtf(vt[c] + 1e-5f);
  float mtc = mt[c], btc = bt[c];
  int part = c / 10; if (part > 5) part = 5;
  const float4* nc4 = (const float4*)ncT;
  const unsigned short* gbase = gridb + (size_t)b * R3 * 64;
  __syncthreads();

  // ---- phase 2 ----
#pragma unroll
  for (int pi = 0; pi < 4; ++pi) {
    int pl = wv * 4 + pi;
    int p = p0 + pl;
    // trilinear interpolation from grid (bf16 rows, 128B coalesced)
    float4 ncv = nc4[p];
    float c0x = floorf(ncv.x), c0y = floorf(ncv.y), c0z = floorf(ncv.z);
    int i0x = (int)c0x, i0y = (int)c0y, i0z = (int)c0z;
    int i1x = min(i0x + 1, 15), i1y = min(i0y + 1, 15), i1z = min(i0z + 1, 15);
    float fx = ncv.x - c0x, fy = ncv.y - c0y, fz = ncv.z - c0z;
    float pv = 0.f;
#pragma unroll
    for (int dx = 0; dx < 2; ++dx)
#pragma unroll
      for (int dy = 0; dy < 2; ++dy)
#pragma unroll
        for (int dz = 0; dz < 2; ++dz) {
          int ix = dx ? i1x : i0x, iy = dy ? i1y : i0y, iz = dz ? i1z : i0z;
          float wg = (dx ? fx : 1.f - fx) * (dy ? fy : 1.f - fy) * (dz ? fz : 1.f - fz);
          pv += wg * b2f(gbase[(size_t)((ix * 16 + iy) * 16 + iz) * 64 + c]);
        }
    // point branch: j + weight from LDS, 16 independent coalesced gathers
    const float* wrow = &wgt[pl * 16 * 7];
    int jv[16];
#pragma unroll
    for (int k = 0; k < 16; ++k) jv[k] = ((const int*)wrow)[k * 7 + 6];
    unsigned short xv[16];
#pragma unroll
    for (int k = 0; k < 16; ++k) xv[k] = xTb[((size_t)(bBase + jv[k])) * 64 + c];
    float acc = -1e30f;
#pragma unroll
    for (int k = 0; k < 16; ++k) {
      float w = wrow[k * 7 + part];
      float v = fmaxf((b2f(xv[k]) * w - mtc) * st + btc, 0.f);
      acc = fmaxf(acc, v);
    }
    res[c][pl] = pv + acc;
  }
  __syncthreads();
  int n0 = grp * 16;
  int i = t & 15, crow = t >> 4;
#pragma unroll
  for (int r2 = 0; r2 < 4; ++r2) {
    int ccw = crow + r2 * 16;
    out[((size_t)b * CC + ccw) * NPTS + n0 + i] = res[ccw][i];
  }
}

extern "C" void kernel_launch(void* const* d_in, const int* in_sizes, int n_in,
                              void* d_out, int out_size, void* d_ws, size_t ws_size,
                              hipStream_t stream) {
  const float* x    = (const float*)d_in[0];
  const float* xyz  = (const float*)d_in[1];
  const int*   idx  = (const int*)d_in[2];
  const float* w3a  = (const float*)d_in[3];
  const float* b3a  = (const float*)d_in[4];
  const float* g3a  = (const float*)d_in[5];
  const float* be3a = (const float*)d_in[6];
  const float* m3a  = (const float*)d_in[7];
  const float* v3a  = (const float*)d_in[8];
  const float* w3b  = (const float*)d_in[9];
  const float* b3b  = (const float*)d_in[10];
  const float* g3b  = (const float*)d_in[11];
  const float* be3b = (const float*)d_in[12];
  const float* m3b  = (const float*)d_in[13];
  const float* v3b  = (const float*)d_in[14];
  const float* wp1  = (const float*)d_in[15];
  const float* gp   = (const float*)d_in[16];
  const float* bp   = (const float*)d_in[17];
  const float* mp   = (const float*)d_in[18];
  const float* vp   = (const float*)d_in[19];
  const float* wp2  = (const float*)d_in[20];
  const float* gt   = (const float*)d_in[21];
  const float* bt   = (const float*)d_in[22];
  const float* mt   = (const float*)d_in[23];
  const float* vt   = (const float*)d_in[24];

  float* ws     = (float*)d_ws;
  float* sumsVC = ws;                          // B*4096*64      = 524288 f32
  float* cnts   = sumsVC + 524288;             // B*4096         =   8192
  float* meanv  = cnts + 8192;                 //                       8
  int*   flat   = (int*)(meanv + 8);           // B*N            =  32768
  float* ncT    = (float*)(flat + 32768);      // B*N*4          = 131072
  float* rec    = ncT + 131072;                // B*N*8          = 262144
  unsigned short* xTb   = (unsigned short*)(rec + 262144);  // B*N*64 bf16
  unsigned short* gridb = xTb + 2097152;                    // B*4096*64 bf16

  // zero sumsVC + cnts (contiguous, 532480 floats = 133120 float4)
  k_mean<<<128, 256, 0, stream>>>(xyz, meanv, (float4*)sumsVC, 133120);
  k_voxel<<<(BB * NPTS) / 256, 256, 0, stream>>>(xyz, meanv, cnts, flat, ncT, rec);
  k_transpose<<<(BB * NPTS) / 64, 256, 0, stream>>>(x, flat, wp1, sumsVC, xTb, rec);
  k_conv<<<BB * CC, 256, 0, stream>>>(sumsVC, cnts, w3a, b3a, g3a, be3a, m3a, v3a,
                                      w3b, b3b, g3b, be3b, m3b, v3b, gridb);
  k_final<<<(BB * NPTS) / 16, 256, 0, stream>>>(xTb, rec, ncT, gridb, idx,
                                                gp, bp, mp, vp, wp2,
                                                gt, bt, mt, vt, (float*)d_out);
}